// Round 9
// baseline (280.288 us; speedup 1.0000x reference)
//
#include <hip/hip_runtime.h>
#include <hip/hip_bf16.h>

#define NTOT (4*256*256)      // 262144 feature rows
#define DIM 384
#define KCL 256               // clusters
#define BM 64                 // rows per block tile
#define TBS 256
#define GRID_MAIN (NTOT/BM)   // 4096 blocks
#define NT 12                 // K-steps of 32
#define EPS 1e-12f

typedef __attribute__((ext_vector_type(8))) _Float16 f16x8;
typedef __attribute__((ext_vector_type(4))) float f32x4;

// ---------------------------------------------------------------------------
// Pre-pass: L2-normalize clusters; emit fp16 hi AND lo residual in FRAGMENT
// ORDER: (j,d) -> ((((t*4+w)*4+n)*4+g)*16+nl)*8+d0  with t=d>>5, g=(d>>3)&3,
// d0=d&7, w=j>>6, n=(j>>4)&3, nl=j&15.  A wave's per-step fragment load is
// one contiguous 1 KiB read per n.
// ---------------------------------------------------------------------------
__global__ void prep_clusters(const float* __restrict__ cc,
                              _Float16* __restrict__ bh,
                              _Float16* __restrict__ bl) {
    int j = blockIdx.x, l = threadIdx.x;   // 256 blocks x 64 lanes
    float v[6]; float ssq = 0.f;
#pragma unroll
    for (int i = 0; i < 6; ++i) { v[i] = cc[j*DIM + l + 64*i]; ssq = fmaf(v[i], v[i], ssq); }
#pragma unroll
    for (int off = 32; off >= 1; off >>= 1) ssq += __shfl_xor(ssq, off);
    float inv = 1.f / fmaxf(sqrtf(ssq), EPS);
    const int w = j >> 6, n = (j >> 4) & 3, nl = j & 15;
#pragma unroll
    for (int i = 0; i < 6; ++i) {
        int d = l + 64 * i;
        float x = v[i] * inv;
        _Float16 h  = (_Float16)x;
        _Float16 lo = (_Float16)(x - (float)h);
        size_t idx = (size_t)((((((d >> 5)*4 + w)*4 + n)*4 + ((d >> 3) & 3))*16 + nl)*8
                              + (d & 7));
        bh[idx] = h;
        bl[idx] = lo;
    }
}

// ---------------------------------------------------------------------------
// Main: 3-pass split-fp16 MFMA GEMM (ah*bh + ah*bl + al*bh, f32 accumulate —
// bit-identical numerics to the proven R2-R6 kernels), ALL-REGISTER streaming:
// no LDS and no barriers in the K-loop. Depth-2 A f32 prefetch (HBM latency
// covered by a full step), single-buffered B (L2-resident, latency covered by
// the interleaved CVT + the co-resident waves).
// ---------------------------------------------------------------------------
__global__ __launch_bounds__(TBS, 2)
void kmeans_main(const float* __restrict__ A,    // [NTOT][384] f32
                 const float* __restrict__ W,    // [NTOT]
                 const _Float16* __restrict__ Bh,// fragment-order fp16 hi
                 const _Float16* __restrict__ Bl,// fragment-order fp16 lo
                 const int*   __restrict__ PA,   // [256]
                 float* __restrict__ out,        // [2*NTOT+1]
                 float* __restrict__ partial)    // [GRID_MAIN]
{
    __shared__ float wvalp[4][BM];
    __shared__ int   wcolp[4][BM];
    __shared__ float sssq[BM];

    const int tid  = threadIdx.x;
    const int wv   = tid >> 6;        // wave -> cluster quarter
    const int lane = tid & 63;
    const int g    = lane >> 4;
    const int l15  = lane & 15;
    const int row0 = blockIdx.x * BM;

    const float* ap = A + (size_t)(row0 + l15) * DIM + g * 8;       // +m*16*DIM +t*32
    const _Float16* bph = Bh + (size_t)wv * 2048 + (size_t)lane * 8;// +t*8192 +n*512
    const _Float16* bpl = Bl + (size_t)wv * 2048 + (size_t)lane * 8;

    f32x4 acc[4][4];
#pragma unroll
    for (int m = 0; m < 4; ++m)
#pragma unroll
        for (int n = 0; n < 4; ++n) acc[m][n] = (f32x4){0.f, 0.f, 0.f, 0.f};
    float ssq4[4] = {0.f, 0.f, 0.f, 0.f};

    float4 tE[4][2], tO[4][2];   // A f32 prefetch slots (even/odd tiles)
    f16x8  bfh[4], bfl[4];       // current B fragments (single-buffered)

    auto LDA = [&](float4 (&t)[4][2], int tt) {
#pragma unroll
        for (int m = 0; m < 4; ++m) {
            t[m][0] = *(const float4*)(ap + (size_t)m*16*DIM + tt*32);
            t[m][1] = *(const float4*)(ap + (size_t)m*16*DIM + tt*32 + 4);
        }
    };
    auto LDB = [&](int tt) {
#pragma unroll
        for (int n = 0; n < 4; ++n) {
            bfh[n] = *(const f16x8*)(bph + (size_t)tt*8192 + n*512);
            bfl[n] = *(const f16x8*)(bpl + (size_t)tt*8192 + n*512);
        }
    };
    // split f32 tile -> hi/lo fp16 frags, accumulate row sumsq for free
    auto CVT = [&](float4 (&t)[4][2], f16x8 (&ah)[4], f16x8 (&al)[4]) {
#pragma unroll
        for (int m = 0; m < 4; ++m) {
            float av[8] = {t[m][0].x, t[m][0].y, t[m][0].z, t[m][0].w,
                           t[m][1].x, t[m][1].y, t[m][1].z, t[m][1].w};
            f16x8 h8, l8;
#pragma unroll
            for (int e = 0; e < 8; ++e) {
                _Float16 hh = (_Float16)av[e];
                h8[e] = hh;
                l8[e] = (_Float16)(av[e] - (float)hh);
                ssq4[m] = fmaf(av[e], av[e], ssq4[m]);
            }
            ah[m] = h8; al[m] = l8;
        }
    };
    // 3 passes, order identical to R2-R6: hh (all m,n), hl, lh
    auto MFMA3 = [&](f16x8 (&ah)[4], f16x8 (&al)[4]) {
        __builtin_amdgcn_s_setprio(1);
#pragma unroll
        for (int m = 0; m < 4; ++m)
#pragma unroll
            for (int n = 0; n < 4; ++n)
                acc[m][n] = __builtin_amdgcn_mfma_f32_16x16x32_f16(ah[m], bfh[n], acc[m][n], 0, 0, 0);
#pragma unroll
        for (int m = 0; m < 4; ++m)
#pragma unroll
            for (int n = 0; n < 4; ++n)
                acc[m][n] = __builtin_amdgcn_mfma_f32_16x16x32_f16(ah[m], bfl[n], acc[m][n], 0, 0, 0);
#pragma unroll
        for (int m = 0; m < 4; ++m)
#pragma unroll
            for (int n = 0; n < 4; ++n)
                acc[m][n] = __builtin_amdgcn_mfma_f32_16x16x32_f16(al[m], bfh[n], acc[m][n], 0, 0, 0);
        __builtin_amdgcn_s_setprio(0);
    };

    // ---- prologue ----
    LDA(tE, 0);
    LDB(0);
    LDA(tO, 1);

    // ---- main loop: zero barriers, register pipeline, unrolled x2 ----
    for (int t = 0; t < NT; t += 2) {
        {   // even step t
            f16x8 ah[4], al[4];
            CVT(tE, ah, al);
            if (t + 2 < NT) LDA(tE, t + 2);
            MFMA3(ah, al);               // uses B(t)
            LDB(t + 1);                  // overwrite bf* (WAR handled by compiler)
        }
        {   // odd step t+1
            f16x8 ah[4], al[4];
            CVT(tO, ah, al);
            if (t + 3 < NT) LDA(tO, t + 3);
            MFMA3(ah, al);               // uses B(t+1)
            if (t + 2 < NT) LDB(t + 2);
        }
    }

    // ---- epilogue ----
    // row sumsq: each wave computed identical per-lane partials; combine the
    // 4 g-groups (lanes l, l^16, l^32, l^48 share l15).
#pragma unroll
    for (int m = 0; m < 4; ++m) {
        ssq4[m] += __shfl_xor(ssq4[m], 16);
        ssq4[m] += __shfl_xor(ssq4[m], 32);
    }
    if (wv == 0 && g == 0) {
#pragma unroll
        for (int m = 0; m < 4; ++m) sssq[16*m + l15] = ssq4[m];
    }

    // per-row argmax over this wave's 64 cols (R5-proven logic).
    // acc[m][n][j] = S[16m + 4g + j][64wv + 16n + l15]
#pragma unroll
    for (int m = 0; m < 4; ++m) {
#pragma unroll
        for (int j = 0; j < 4; ++j) {
            float best = acc[m][0][j];
            int   bc   = 64*wv + l15;
#pragma unroll
            for (int n = 1; n < 4; ++n) {
                float v = acc[m][n][j];
                int   c = 64*wv + 16*n + l15;
                if (v > best) { best = v; bc = c; }
            }
#pragma unroll
            for (int off = 1; off < 16; off <<= 1) {
                float ov = __shfl_xor(best, off);
                int   oc = __shfl_xor(bc, off);
                if (ov > best || (ov == best && oc < bc)) { best = ov; bc = oc; }
            }
            if (l15 == 0) {
                wvalp[wv][16*m + 4*g + j] = best;
                wcolp[wv][16*m + 4*g + j] = bc;
            }
        }
    }
    __syncthreads();

    // combine 4 waves per row, write outputs, block loss partial
    if (tid < BM) {
        int r = tid;
        float best = wvalp[0][r]; int bc = wcolp[0][r];
#pragma unroll
        for (int w = 1; w < 4; ++w) {
            float ov = wvalp[w][r]; int oc = wcolp[w][r];
            if (ov > best || (ov == best && oc < bc)) { best = ov; bc = oc; }
        }
        float inv = 1.f / fmaxf(sqrtf(sssq[r]), EPS);
        int gr = row0 + r;
        out[gr]        = (float)bc;
        out[NTOT + gr] = (float)PA[bc];
        float lsum = -(best * inv) * W[gr];
#pragma unroll
        for (int off = 32; off >= 1; off >>= 1) lsum += __shfl_xor(lsum, off);
        if (tid == 0) partial[blockIdx.x] = lsum;
    }
}

// ---------------------------------------------------------------------------
// Deterministic final loss reduction: 4096 partials -> mean
// ---------------------------------------------------------------------------
__global__ void loss_reduce(const float* __restrict__ partial, float* __restrict__ out_loss) {
    __shared__ float s[256];
    float v = 0.f;
    for (int i = threadIdx.x; i < GRID_MAIN; i += 256) v += partial[i];
    s[threadIdx.x] = v;
    __syncthreads();
    for (int off = 128; off >= 1; off >>= 1) {
        if ((int)threadIdx.x < off) s[threadIdx.x] += s[threadIdx.x + off];
        __syncthreads();
    }
    if (threadIdx.x == 0) out_loss[0] = s[0] * (1.0f / (float)NTOT);
}

extern "C" void kernel_launch(void* const* d_in, const int* in_sizes, int n_in,
                              void* d_out, int out_size, void* d_ws, size_t ws_size,
                              hipStream_t stream) {
    const float* features = (const float*)d_in[0];
    const float* weight   = (const float*)d_in[1];
    const float* cc       = (const float*)d_in[2];
    const int*   pa       = (const int*)d_in[3];
    float* out = (float*)d_out;

    _Float16* bh   = (_Float16*)d_ws;              // 192 KiB fragment-order hi
    _Float16* bl   = bh + KCL * DIM;               // 192 KiB fragment-order lo
    float* partial = (float*)(bl + KCL * DIM);     // 16 KiB

    hipLaunchKernelGGL(prep_clusters, dim3(KCL), dim3(64), 0, stream, cc, bh, bl);
    hipLaunchKernelGGL(kmeans_main, dim3(GRID_MAIN), dim3(TBS), 0, stream,
                       features, weight, bh, bl, pa, out, partial);
    hipLaunchKernelGGL(loss_reduce, dim3(1), dim3(256), 0, stream, partial, out + 2 * NTOT);
}

// Round 10
// 202.280 us; speedup vs baseline: 1.3856x; 1.3856x over previous
//
#include <hip/hip_runtime.h>
#include <hip/hip_bf16.h>

#define NTOT (4*256*256)      // 262144 feature rows
#define DIM 384
#define KCL 256               // clusters
#define BM 64                 // rows per block tile
#define TBS 256
#define GRID_MAIN (NTOT/BM)   // 4096 blocks
#define NT 12                 // K-steps of 32
#define EPS 1e-12f

// LDS map (bytes), total 40960 -> 3-4 blocks/CU
#define AHI    0              // A hi  : 64 rows x 4 slots x 16B = 4 KiB (swizzled)
#define ALO    4096           // A lo  : 4 KiB
#define BH_OFF 8192           // B hi  : 4 waves x 4 KiB (wave-owned quarters)
#define BL_OFF 24576          // B lo  : 16 KiB
#define SMEM_BYTES 40960

typedef __attribute__((ext_vector_type(8))) _Float16 f16x8;
typedef __attribute__((ext_vector_type(4))) float f32x4;

__device__ __forceinline__ void async_copy16(const void* gptr, void* lptr) {
    __builtin_amdgcn_global_load_lds(
        (const __attribute__((address_space(1))) unsigned int*)gptr,
        (__attribute__((address_space(3))) unsigned int*)lptr, 16, 0, 0);
}

// ---------------------------------------------------------------------------
// Pre-pass: L2-normalize clusters; emit fp16 hi+lo residual in FRAGMENT ORDER:
// (j,d) -> ((((t*4+w)*4+n)*4+g)*16+nl)*8+d0, t=d>>5, g=(d>>3)&3, d0=d&7,
// w=j>>6, n=(j>>4)&3, nl=j&15.  Per (t,w): 4 KiB contiguous, lane-linear.
// ---------------------------------------------------------------------------
__global__ void prep_clusters(const float* __restrict__ cc,
                              _Float16* __restrict__ bh,
                              _Float16* __restrict__ bl) {
    int j = blockIdx.x, l = threadIdx.x;   // 256 blocks x 64 lanes
    float v[6]; float ssq = 0.f;
#pragma unroll
    for (int i = 0; i < 6; ++i) { v[i] = cc[j*DIM + l + 64*i]; ssq = fmaf(v[i], v[i], ssq); }
#pragma unroll
    for (int off = 32; off >= 1; off >>= 1) ssq += __shfl_xor(ssq, off);
    float inv = 1.f / fmaxf(sqrtf(ssq), EPS);
    const int w = j >> 6, n = (j >> 4) & 3, nl = j & 15;
#pragma unroll
    for (int i = 0; i < 6; ++i) {
        int d = l + 64 * i;
        float x = v[i] * inv;
        _Float16 h  = (_Float16)x;
        _Float16 lo = (_Float16)(x - (float)h);
        size_t idx = (size_t)((((((d >> 5)*4 + w)*4 + n)*4 + ((d >> 3) & 3))*16 + nl)*8
                              + (d & 7));
        bh[idx] = h;
        bl[idx] = lo;
    }
}

// ---------------------------------------------------------------------------
// Main: 3-pass split-fp16 MFMA GEMM (bit-identical numerics to R2-R6).
// Counted-vmcnt pipeline: barriers drain lgkm ONLY; each wave stages its own
// B quarter (gl_lds) and guards it with its own vmcnt; A is single-buffered
// LDS with depth-2 f32 register prefetch flying across barriers.
// ---------------------------------------------------------------------------
__global__ __launch_bounds__(TBS, 3)
void kmeans_main(const float* __restrict__ A,    // [NTOT][384] f32
                 const float* __restrict__ W,    // [NTOT]
                 const _Float16* __restrict__ Bh,// fragment-order fp16 hi
                 const _Float16* __restrict__ Bl,// fragment-order fp16 lo
                 const int*   __restrict__ PA,   // [256]
                 float* __restrict__ out,        // [2*NTOT+1]
                 float* __restrict__ partial)    // [GRID_MAIN]
{
    __shared__ unsigned char smem[SMEM_BYTES];

    const int tid  = threadIdx.x;
    const int wv   = tid >> 6;        // wave -> cluster quarter [64wv, 64wv+64)
    const int lane = tid & 63;
    const int g    = lane >> 4;
    const int l15  = lane & 15;
    const int sw   = (l15 >> 1) & 3;  // A read-side swizzle (R3/R5, 0-conflict)
    const int row0 = blockIdx.x * BM;
    const int arow = tid >> 2, achk = tid & 3;
    const int awb  = (((arow << 2) + (achk ^ ((arow >> 1) & 3))) << 4);
    const int fa   = l15 * 64 + ((g ^ sw) << 4);      // A frag base (+m*1024)
    const int fb   = wv * 4096 + lane * 16;           // B frag/stage base (+n*1024)

    const float* ap = A + (size_t)(row0 + arow) * DIM + achk * 8;
    const unsigned char* bsh = (const unsigned char*)Bh + (size_t)(wv * 4) * 1024 + lane * 16;
    const unsigned char* bsl = (const unsigned char*)Bl + (size_t)(wv * 4) * 1024 + lane * 16;

    f32x4 acc[4][4];
#pragma unroll
    for (int m = 0; m < 4; ++m)
#pragma unroll
        for (int n = 0; n < 4; ++n) acc[m][n] = (f32x4){0.f, 0.f, 0.f, 0.f};
    float ssq = 0.f;

    // wave stages ITS OWN 8 KiB quarter: 8 gl_lds, lane-linear dest (m104-safe)
    auto stageB = [&](int t) {
#pragma unroll
        for (int n = 0; n < 4; ++n) {
            async_copy16(bsh + (size_t)(t * 16 + n) * 1024, smem + BH_OFF + fb + n * 1024);
            async_copy16(bsl + (size_t)(t * 16 + n) * 1024, smem + BL_OFF + fb + n * 1024);
        }
    };
    auto writeA = [&](const float4& x0, const float4& x1) {
        float av[8] = {x0.x, x0.y, x0.z, x0.w, x1.x, x1.y, x1.z, x1.w};
        f16x8 h8, l8;
#pragma unroll
        for (int e = 0; e < 8; ++e) {
            _Float16 hh = (_Float16)av[e];
            h8[e] = hh;
            l8[e] = (_Float16)(av[e] - (float)hh);
            ssq = fmaf(av[e], av[e], ssq);
        }
        *(f16x8*)(smem + AHI + awb) = h8;
        *(f16x8*)(smem + ALO + awb) = l8;
    };

    float4 rA0x, rA0y, rA1x, rA1y;   // tile slots: slot s holds tile with tile&1==s

    // ---- prologue: tile0 -> A buf, stage B(0), tile1 -> regs ----
    rA0x = *(const float4*)(ap);
    rA0y = *(const float4*)(ap + 4);
    stageB(0);
    writeA(rA0x, rA0y);              // compiler waits only the 2 rA0 loads
    rA1x = *(const float4*)(ap + 32);
    rA1y = *(const float4*)(ap + 32 + 4);
    asm volatile("s_waitcnt lgkmcnt(0)" ::: "memory");
    __builtin_amdgcn_s_barrier();

    // ---- main loop: fully unrolled, compile-time t ----
#pragma unroll
    for (int t = 0; t < NT; ++t) {
        // my outstanding vmem: stageB(t)[8 oldest] + (t<NT-1 ? rA(t+1)[2] : 0)
        if (t < NT - 1) asm volatile("s_waitcnt vmcnt(2)" ::: "memory");
        else            asm volatile("s_waitcnt vmcnt(0)" ::: "memory");

        // fragment reads (A swizzled, B lane-linear) -> regs
        f16x8 ahf[4], alf[4], bfh[4], bfl[4];
#pragma unroll
        for (int m = 0; m < 4; ++m) {
            ahf[m] = *(const f16x8*)(smem + AHI + fa + m * 1024);
            alf[m] = *(const f16x8*)(smem + ALO + fa + m * 1024);
        }
#pragma unroll
        for (int n = 0; n < 4; ++n) {
            bfh[n] = *(const f16x8*)(smem + BH_OFF + fb + n * 1024);
            bfl[n] = *(const f16x8*)(smem + BL_OFF + fb + n * 1024);
        }
        asm volatile("s_waitcnt lgkmcnt(0)" ::: "memory");
        __builtin_amdgcn_s_barrier();          // all waves' A reads retired

        if (t < NT - 1) {
            // publish A(t+1) (ds_write), restage my B quarter, prefetch A(t+3-1)
            if (((t + 1) & 1) == 0) writeA(rA0x, rA0y); else writeA(rA1x, rA1y);
            stageB(t + 1);
            if (t + 2 < NT) {
                if (((t + 2) & 1) == 0) {
                    rA0x = *(const float4*)(ap + (t + 2) * 32);
                    rA0y = *(const float4*)(ap + (t + 2) * 32 + 4);
                } else {
                    rA1x = *(const float4*)(ap + (t + 2) * 32);
                    rA1y = *(const float4*)(ap + (t + 2) * 32 + 4);
                }
            }
        }

        // 3 passes, order identical to R2-R6 (bit-identical accumulation)
        __builtin_amdgcn_s_setprio(1);
#pragma unroll
        for (int m = 0; m < 4; ++m)
#pragma unroll
            for (int n = 0; n < 4; ++n)
                acc[m][n] = __builtin_amdgcn_mfma_f32_16x16x32_f16(ahf[m], bfh[n], acc[m][n], 0, 0, 0);
#pragma unroll
        for (int m = 0; m < 4; ++m)
#pragma unroll
            for (int n = 0; n < 4; ++n)
                acc[m][n] = __builtin_amdgcn_mfma_f32_16x16x32_f16(ahf[m], bfl[n], acc[m][n], 0, 0, 0);
#pragma unroll
        for (int m = 0; m < 4; ++m)
#pragma unroll
            for (int n = 0; n < 4; ++n)
                acc[m][n] = __builtin_amdgcn_mfma_f32_16x16x32_f16(alf[m], bfh[n], acc[m][n], 0, 0, 0);
        __builtin_amdgcn_s_setprio(0);

        if (t < NT - 1) {
            asm volatile("s_waitcnt lgkmcnt(0)" ::: "memory");  // my A ds_writes retired
            __builtin_amdgcn_s_barrier();                        // A(t+1) published
        }
    }
    __syncthreads();   // full drain before overlaying smem

    // ---- epilogue (overlay scratch on smem; R5-proven logic) ----
    float* rowssq = (float*)smem;                 // 256 B
    float* wvalp  = (float*)(smem + 256);         // 1 KiB
    int*   wcolp  = (int*)(smem + 1280);          // 1 KiB

    ssq += __shfl_xor(ssq, 1);
    ssq += __shfl_xor(ssq, 2);
    if (achk == 0) rowssq[arow] = ssq;

    // per-row argmax. acc[m][n][j] = S[16m + 4g + j][64wv + 16n + l15]
#pragma unroll
    for (int m = 0; m < 4; ++m) {
#pragma unroll
        for (int j = 0; j < 4; ++j) {
            float best = acc[m][0][j];
            int   bc   = 64*wv + l15;
#pragma unroll
            for (int n = 1; n < 4; ++n) {
                float v = acc[m][n][j];
                int   c = 64*wv + 16*n + l15;
                if (v > best) { best = v; bc = c; }
            }
#pragma unroll
            for (int off = 1; off < 16; off <<= 1) {
                float ov = __shfl_xor(best, off);
                int   oc = __shfl_xor(bc, off);
                if (ov > best || (ov == best && oc < bc)) { best = ov; bc = oc; }
            }
            if (l15 == 0) {
                wvalp[wv * BM + 16*m + 4*g + j] = best;
                wcolp[wv * BM + 16*m + 4*g + j] = bc;
            }
        }
    }
    __syncthreads();

    if (tid < BM) {
        int r = tid;
        float best = wvalp[r]; int bc = wcolp[r];
#pragma unroll
        for (int w = 1; w < 4; ++w) {
            float ov = wvalp[w * BM + r]; int oc = wcolp[w * BM + r];
            if (ov > best || (ov == best && oc < bc)) { best = ov; bc = oc; }
        }
        float inv = 1.f / fmaxf(sqrtf(rowssq[r]), EPS);
        int gr = row0 + r;
        out[gr]        = (float)bc;
        out[NTOT + gr] = (float)PA[bc];
        float lsum = -(best * inv) * W[gr];
#pragma unroll
        for (int off = 32; off >= 1; off >>= 1) lsum += __shfl_xor(lsum, off);
        if (tid == 0) partial[blockIdx.x] = lsum;
    }
}

// ---------------------------------------------------------------------------
// Deterministic final loss reduction: 4096 partials -> mean
// ---------------------------------------------------------------------------
__global__ void loss_reduce(const float* __restrict__ partial, float* __restrict__ out_loss) {
    __shared__ float s[256];
    float v = 0.f;
    for (int i = threadIdx.x; i < GRID_MAIN; i += 256) v += partial[i];
    s[threadIdx.x] = v;
    __syncthreads();
    for (int off = 128; off >= 1; off >>= 1) {
        if ((int)threadIdx.x < off) s[threadIdx.x] += s[threadIdx.x + off];
        __syncthreads();
    }
    if (threadIdx.x == 0) out_loss[0] = s[0] * (1.0f / (float)NTOT);
}

extern "C" void kernel_launch(void* const* d_in, const int* in_sizes, int n_in,
                              void* d_out, int out_size, void* d_ws, size_t ws_size,
                              hipStream_t stream) {
    const float* features = (const float*)d_in[0];
    const float* weight   = (const float*)d_in[1];
    const float* cc       = (const float*)d_in[2];
    const int*   pa       = (const int*)d_in[3];
    float* out = (float*)d_out;

    _Float16* bh   = (_Float16*)d_ws;              // 192 KiB fragment-order hi
    _Float16* bl   = bh + KCL * DIM;               // 192 KiB fragment-order lo
    float* partial = (float*)(bl + KCL * DIM);     // 16 KiB

    hipLaunchKernelGGL(prep_clusters, dim3(KCL), dim3(64), 0, stream, cc, bh, bl);
    hipLaunchKernelGGL(kmeans_main, dim3(GRID_MAIN), dim3(TBS), 0, stream,
                       features, weight, bh, bl, pa, out, partial);
    hipLaunchKernelGGL(loss_reduce, dim3(1), dim3(256), 0, stream, partial, out + 2 * NTOT);
}

// Round 11
// 182.382 us; speedup vs baseline: 1.5368x; 1.1091x over previous
//
#include <hip/hip_runtime.h>
#include <hip/hip_bf16.h>

#define NTOT (4*256*256)      // 262144 feature rows
#define DIM 384
#define KCL 256               // clusters
#define BM 64                 // rows per block tile
#define TBS 256
#define GRID_MAIN (NTOT/BM)   // 4096 blocks
#define NT 12                 // K-steps of 32
#define EPS 1e-12f

// LDS: A double-buffer only. buf p at p*8192: hi +0, lo +4096. Total 16 KiB.
#define AB(p) ((p) * 8192)
#define SMEM_BYTES 16384

typedef __attribute__((ext_vector_type(8))) _Float16 f16x8;
typedef __attribute__((ext_vector_type(4))) float f32x4;

// ---------------------------------------------------------------------------
// Pre-pass: L2-normalize clusters; emit fp16 hi+lo residual in FRAGMENT ORDER:
// (j,d) -> ((((t*4+w)*4+n)*4+g)*16+nl)*8+d0, t=d>>5, g=(d>>3)&3, d0=d&7,
// w=j>>6, n=(j>>4)&3, nl=j&15.  Per (t,w,n): 1 KiB contiguous, lane-linear.
// ---------------------------------------------------------------------------
__global__ void prep_clusters(const float* __restrict__ cc,
                              _Float16* __restrict__ bh,
                              _Float16* __restrict__ bl) {
    int j = blockIdx.x, l = threadIdx.x;   // 256 blocks x 64 lanes
    float v[6]; float ssq = 0.f;
#pragma unroll
    for (int i = 0; i < 6; ++i) { v[i] = cc[j*DIM + l + 64*i]; ssq = fmaf(v[i], v[i], ssq); }
#pragma unroll
    for (int off = 32; off >= 1; off >>= 1) ssq += __shfl_xor(ssq, off);
    float inv = 1.f / fmaxf(sqrtf(ssq), EPS);
    const int w = j >> 6, n = (j >> 4) & 3, nl = j & 15;
#pragma unroll
    for (int i = 0; i < 6; ++i) {
        int d = l + 64 * i;
        float x = v[i] * inv;
        _Float16 h  = (_Float16)x;
        _Float16 lo = (_Float16)(x - (float)h);
        size_t idx = (size_t)((((((d >> 5)*4 + w)*4 + n)*4 + ((d >> 3) & 3))*16 + nl)*8
                              + (d & 7));
        bh[idx] = h;
        bl[idx] = lo;
    }
}

// ---------------------------------------------------------------------------
// Main: 3-pass split-fp16 MFMA GEMM (bit-identical numerics to R2-R6/R10).
// B: global->register per wave (L2-resident, fragment-order, coalesced 1KB),
//    issued right after last use in the previous MFMA block; compiler emits
//    precise counted vmcnt waits (registers, not LDS-DMA).
// A: LDS double-buffer (16 KiB), depth-2 f32 register prefetch, ONE
//    lgkm-only barrier per K-step (no vmcnt drain at barriers).
// ---------------------------------------------------------------------------
__global__ __launch_bounds__(TBS, 2)
void kmeans_main(const float* __restrict__ A,    // [NTOT][384] f32
                 const float* __restrict__ W,    // [NTOT]
                 const _Float16* __restrict__ Bh,// fragment-order fp16 hi
                 const _Float16* __restrict__ Bl,// fragment-order fp16 lo
                 const int*   __restrict__ PA,   // [256]
                 float* __restrict__ out,        // [2*NTOT+1]
                 float* __restrict__ partial)    // [GRID_MAIN]
{
    __shared__ unsigned char smem[SMEM_BYTES];

    const int tid  = threadIdx.x;
    const int wv   = tid >> 6;        // wave -> cluster quarter [64wv, 64wv+64)
    const int lane = tid & 63;
    const int g    = lane >> 4;
    const int l15  = lane & 15;
    const int sw   = (l15 >> 1) & 3;  // A read-side swizzle (R3/R5/R10 proven)
    const int row0 = blockIdx.x * BM;
    const int arow = tid >> 2, achk = tid & 3;
    const int awb  = (((arow << 2) + (achk ^ ((arow >> 1) & 3))) << 4);
    const int fa   = l15 * 64 + ((g ^ sw) << 4);      // A frag base (+m*1024)

    const float* ap = A + (size_t)(row0 + arow) * DIM + achk * 8;
    const unsigned char* bsh = (const unsigned char*)Bh + (size_t)(wv * 4) * 1024 + lane * 16;
    const unsigned char* bsl = (const unsigned char*)Bl + (size_t)(wv * 4) * 1024 + lane * 16;

    f32x4 acc[4][4];
#pragma unroll
    for (int m = 0; m < 4; ++m)
#pragma unroll
        for (int n = 0; n < 4; ++n) acc[m][n] = (f32x4){0.f, 0.f, 0.f, 0.f};
    float ssq = 0.f;

    f16x8  bfh[4], bfl[4];       // current B fragments (registers, single set)
    float4 sA[2][2];             // A f32 prefetch slots by tile parity

    auto LDA = [&](int s, int tt) {
        sA[s][0] = *(const float4*)(ap + tt * 32);
        sA[s][1] = *(const float4*)(ap + tt * 32 + 4);
    };
    auto LDBH = [&](int tt) {
#pragma unroll
        for (int n = 0; n < 4; ++n)
            bfh[n] = *(const f16x8*)(bsh + (size_t)(tt * 16 + n) * 1024);
    };
    auto LDBL = [&](int tt) {
#pragma unroll
        for (int n = 0; n < 4; ++n)
            bfl[n] = *(const f16x8*)(bsl + (size_t)(tt * 16 + n) * 1024);
    };
    // split f32 tile (slot s) -> hi/lo fp16, swizzled ds_write to buf p
    auto CVTW = [&](int s, int p) {
        float av[8] = {sA[s][0].x, sA[s][0].y, sA[s][0].z, sA[s][0].w,
                       sA[s][1].x, sA[s][1].y, sA[s][1].z, sA[s][1].w};
        f16x8 h8, l8;
#pragma unroll
        for (int e = 0; e < 8; ++e) {
            _Float16 hh = (_Float16)av[e];
            h8[e] = hh;
            l8[e] = (_Float16)(av[e] - (float)hh);
            ssq = fmaf(av[e], av[e], ssq);
        }
        *(f16x8*)(smem + AB(p) + awb) = h8;
        *(f16x8*)(smem + AB(p) + 4096 + awb) = l8;
    };

    // ---- prologue: tile0 -> buf0, B(0) -> regs, tile1 -> slot1 ----
    LDA(0, 0);
    LDBL(0); LDBH(0);
    LDA(1, 1);
    CVTW(0, 0);                  // compiler waits only the slot-0 loads
    asm volatile("s_waitcnt lgkmcnt(0)" ::: "memory");
    __builtin_amdgcn_s_barrier();

    // ---- main loop: fully unrolled; ONE lgkm-barrier per step ----
#pragma unroll
    for (int t = 0; t < NT; ++t) {
        if (t + 2 < NT) LDA((t + 2) & 1, t + 2);   // depth-2 A prefetch (HBM)

        f16x8 ahf[4], alf[4];
#pragma unroll
        for (int m = 0; m < 4; ++m) {
            ahf[m] = *(const f16x8*)(smem + AB(t & 1) + fa + m * 1024);
            alf[m] = *(const f16x8*)(smem + AB(t & 1) + 4096 + fa + m * 1024);
        }
        if (t + 1 < NT) CVTW((t + 1) & 1, (t + 1) & 1);  // publish A(t+1) -> other buf
        asm volatile("s_waitcnt lgkmcnt(0)" ::: "memory");
        __builtin_amdgcn_s_barrier();

        // 3 passes, order identical to R2-R6 (bit-identical accumulation)
        __builtin_amdgcn_s_setprio(1);
#pragma unroll
        for (int m = 0; m < 4; ++m)
#pragma unroll
            for (int n = 0; n < 4; ++n)
                acc[m][n] = __builtin_amdgcn_mfma_f32_16x16x32_f16(ahf[m], bfh[n], acc[m][n], 0, 0, 0);
#pragma unroll
        for (int m = 0; m < 4; ++m)
#pragma unroll
            for (int n = 0; n < 4; ++n)
                acc[m][n] = __builtin_amdgcn_mfma_f32_16x16x32_f16(ahf[m], bfl[n], acc[m][n], 0, 0, 0);
        __builtin_amdgcn_s_setprio(0);
        if (t + 1 < NT) LDBL(t + 1);               // bfl dead after pass 2
        __builtin_amdgcn_s_setprio(1);
#pragma unroll
        for (int m = 0; m < 4; ++m)
#pragma unroll
            for (int n = 0; n < 4; ++n)
                acc[m][n] = __builtin_amdgcn_mfma_f32_16x16x32_f16(alf[m], bfh[n], acc[m][n], 0, 0, 0);
        __builtin_amdgcn_s_setprio(0);
        if (t + 1 < NT) LDBH(t + 1);               // bfh dead after pass 3
    }
    __syncthreads();   // full drain before overlaying smem

    // ---- epilogue (overlay scratch on smem; R5/R10-proven logic) ----
    float* rowssq = (float*)smem;                 // 256 B
    float* wvalp  = (float*)(smem + 256);         // 1 KiB
    int*   wcolp  = (int*)(smem + 1280);          // 1 KiB

    ssq += __shfl_xor(ssq, 1);
    ssq += __shfl_xor(ssq, 2);
    if (achk == 0) rowssq[arow] = ssq;

    // per-row argmax. acc[m][n][j] = S[16m + 4g + j][64wv + 16n + l15]
#pragma unroll
    for (int m = 0; m < 4; ++m) {
#pragma unroll
        for (int j = 0; j < 4; ++j) {
            float best = acc[m][0][j];
            int   bc   = 64*wv + l15;
#pragma unroll
            for (int n = 1; n < 4; ++n) {
                float v = acc[m][n][j];
                int   c = 64*wv + 16*n + l15;
                if (v > best) { best = v; bc = c; }
            }
#pragma unroll
            for (int off = 1; off < 16; off <<= 1) {
                float ov = __shfl_xor(best, off);
                int   oc = __shfl_xor(bc, off);
                if (ov > best || (ov == best && oc < bc)) { best = ov; bc = oc; }
            }
            if (l15 == 0) {
                wvalp[wv * BM + 16*m + 4*g + j] = best;
                wcolp[wv * BM + 16*m + 4*g + j] = bc;
            }
        }
    }
    __syncthreads();

    if (tid < BM) {
        int r = tid;
        float best = wvalp[r]; int bc = wcolp[r];
#pragma unroll
        for (int w = 1; w < 4; ++w) {
            float ov = wvalp[w * BM + r]; int oc = wcolp[w * BM + r];
            if (ov > best || (ov == best && oc < bc)) { best = ov; bc = oc; }
        }
        float inv = 1.f / fmaxf(sqrtf(rowssq[r]), EPS);
        int gr = row0 + r;
        out[gr]        = (float)bc;
        out[NTOT + gr] = (float)PA[bc];
        float lsum = -(best * inv) * W[gr];
#pragma unroll
        for (int off = 32; off >= 1; off >>= 1) lsum += __shfl_xor(lsum, off);
        if (tid == 0) partial[blockIdx.x] = lsum;
    }
}

// ---------------------------------------------------------------------------
// Deterministic final loss reduction: 4096 partials -> mean
// ---------------------------------------------------------------------------
__global__ void loss_reduce(const float* __restrict__ partial, float* __restrict__ out_loss) {
    __shared__ float s[256];
    float v = 0.f;
    for (int i = threadIdx.x; i < GRID_MAIN; i += 256) v += partial[i];
    s[threadIdx.x] = v;
    __syncthreads();
    for (int off = 128; off >= 1; off >>= 1) {
        if ((int)threadIdx.x < off) s[threadIdx.x] += s[threadIdx.x + off];
        __syncthreads();
    }
    if (threadIdx.x == 0) out_loss[0] = s[0] * (1.0f / (float)NTOT);
}

extern "C" void kernel_launch(void* const* d_in, const int* in_sizes, int n_in,
                              void* d_out, int out_size, void* d_ws, size_t ws_size,
                              hipStream_t stream) {
    const float* features = (const float*)d_in[0];
    const float* weight   = (const float*)d_in[1];
    const float* cc       = (const float*)d_in[2];
    const int*   pa       = (const int*)d_in[3];
    float* out = (float*)d_out;

    _Float16* bh   = (_Float16*)d_ws;              // 192 KiB fragment-order hi
    _Float16* bl   = bh + KCL * DIM;               // 192 KiB fragment-order lo
    float* partial = (float*)(bl + KCL * DIM);     // 16 KiB

    hipLaunchKernelGGL(prep_clusters, dim3(KCL), dim3(64), 0, stream, cc, bh, bl);
    hipLaunchKernelGGL(kmeans_main, dim3(GRID_MAIN), dim3(TBS), 0, stream,
                       features, weight, bh, bl, pa, out, partial);
    hipLaunchKernelGGL(loss_reduce, dim3(1), dim3(256), 0, stream, partial, out + 2 * NTOT);
}

// Round 12
// 182.380 us; speedup vs baseline: 1.5368x; 1.0000x over previous
//
#include <hip/hip_runtime.h>
#include <hip/hip_bf16.h>

#define NTOT (4*256*256)      // 262144 feature rows
#define DIM 384
#define KCL 256               // clusters
#define BM 64                 // rows per block tile
#define TBS 256
#define GRID_MAIN (NTOT/BM)   // 4096 blocks
#define NT 12                 // K-steps of 32
#define EPS 1e-12f

// LDS: A double-buffer only. buf p at p*8192: hi +0, lo +4096. Total 16 KiB.
#define AB(p) ((p) * 8192)
#define SMEM_BYTES 16384

typedef __attribute__((ext_vector_type(8))) _Float16 f16x8;
typedef __attribute__((ext_vector_type(4))) float f32x4;

// ---------------------------------------------------------------------------
// Pre-pass: L2-normalize clusters; emit fp16 hi+lo residual in FRAGMENT ORDER:
// (j,d) -> ((((t*4+w)*4+n)*4+g)*16+nl)*8+d0, t=d>>5, g=(d>>3)&3, d0=d&7,
// w=j>>6, n=(j>>4)&3, nl=j&15.  Per (t,w,n): 1 KiB contiguous, lane-linear.
// ---------------------------------------------------------------------------
__global__ void prep_clusters(const float* __restrict__ cc,
                              _Float16* __restrict__ bh,
                              _Float16* __restrict__ bl) {
    int j = blockIdx.x, l = threadIdx.x;   // 256 blocks x 64 lanes
    float v[6]; float ssq = 0.f;
#pragma unroll
    for (int i = 0; i < 6; ++i) { v[i] = cc[j*DIM + l + 64*i]; ssq = fmaf(v[i], v[i], ssq); }
#pragma unroll
    for (int off = 32; off >= 1; off >>= 1) ssq += __shfl_xor(ssq, off);
    float inv = 1.f / fmaxf(sqrtf(ssq), EPS);
    const int w = j >> 6, n = (j >> 4) & 3, nl = j & 15;
#pragma unroll
    for (int i = 0; i < 6; ++i) {
        int d = l + 64 * i;
        float x = v[i] * inv;
        _Float16 h  = (_Float16)x;
        _Float16 lo = (_Float16)(x - (float)h);
        size_t idx = (size_t)((((((d >> 5)*4 + w)*4 + n)*4 + ((d >> 3) & 3))*16 + nl)*8
                              + (d & 7));
        bh[idx] = h;
        bl[idx] = lo;
    }
}

// ---------------------------------------------------------------------------
// Main: 3-pass split-fp16 MFMA GEMM (bit-identical numerics to R2-R6/R10/R11).
// B: global->register per wave (L2-resident, fragment-order, coalesced 1KB),
//    issued right after last use in the previous MFMA block; compiler emits
//    precise counted vmcnt waits.
// A: LDS double-buffer (16 KiB), depth-2 f32 register prefetch, ONE
//    lgkm-only barrier per K-step (no vmcnt drain at barriers).
// R12 change vs R11: __launch_bounds__(256,3) -> 3 waves/SIMD (live-reg
// estimate ~160 fits the 170-VGPR cap; occupancy was the R11 limiter).
// ---------------------------------------------------------------------------
__global__ __launch_bounds__(TBS, 3)
void kmeans_main(const float* __restrict__ A,    // [NTOT][384] f32
                 const float* __restrict__ W,    // [NTOT]
                 const _Float16* __restrict__ Bh,// fragment-order fp16 hi
                 const _Float16* __restrict__ Bl,// fragment-order fp16 lo
                 const int*   __restrict__ PA,   // [256]
                 float* __restrict__ out,        // [2*NTOT+1]
                 float* __restrict__ partial)    // [GRID_MAIN]
{
    __shared__ unsigned char smem[SMEM_BYTES];

    const int tid  = threadIdx.x;
    const int wv   = tid >> 6;        // wave -> cluster quarter [64wv, 64wv+64)
    const int lane = tid & 63;
    const int g    = lane >> 4;
    const int l15  = lane & 15;
    const int sw   = (l15 >> 1) & 3;  // A read-side swizzle (R3/R5/R10 proven)
    const int row0 = blockIdx.x * BM;
    const int arow = tid >> 2, achk = tid & 3;
    const int awb  = (((arow << 2) + (achk ^ ((arow >> 1) & 3))) << 4);
    const int fa   = l15 * 64 + ((g ^ sw) << 4);      // A frag base (+m*1024)

    const float* ap = A + (size_t)(row0 + arow) * DIM + achk * 8;
    const unsigned char* bsh = (const unsigned char*)Bh + (size_t)(wv * 4) * 1024 + lane * 16;
    const unsigned char* bsl = (const unsigned char*)Bl + (size_t)(wv * 4) * 1024 + lane * 16;

    f32x4 acc[4][4];
#pragma unroll
    for (int m = 0; m < 4; ++m)
#pragma unroll
        for (int n = 0; n < 4; ++n) acc[m][n] = (f32x4){0.f, 0.f, 0.f, 0.f};
    float ssq = 0.f;

    f16x8  bfh[4], bfl[4];       // current B fragments (registers, single set)
    float4 sA[2][2];             // A f32 prefetch slots by tile parity

    auto LDA = [&](int s, int tt) {
        sA[s][0] = *(const float4*)(ap + tt * 32);
        sA[s][1] = *(const float4*)(ap + tt * 32 + 4);
    };
    auto LDBH = [&](int tt) {
#pragma unroll
        for (int n = 0; n < 4; ++n)
            bfh[n] = *(const f16x8*)(bsh + (size_t)(tt * 16 + n) * 1024);
    };
    auto LDBL = [&](int tt) {
#pragma unroll
        for (int n = 0; n < 4; ++n)
            bfl[n] = *(const f16x8*)(bsl + (size_t)(tt * 16 + n) * 1024);
    };
    // split f32 tile (slot s) -> hi/lo fp16, swizzled ds_write to buf p
    auto CVTW = [&](int s, int p) {
        float av[8] = {sA[s][0].x, sA[s][0].y, sA[s][0].z, sA[s][0].w,
                       sA[s][1].x, sA[s][1].y, sA[s][1].z, sA[s][1].w};
        f16x8 h8, l8;
#pragma unroll
        for (int e = 0; e < 8; ++e) {
            _Float16 hh = (_Float16)av[e];
            h8[e] = hh;
            l8[e] = (_Float16)(av[e] - (float)hh);
            ssq = fmaf(av[e], av[e], ssq);
        }
        *(f16x8*)(smem + AB(p) + awb) = h8;
        *(f16x8*)(smem + AB(p) + 4096 + awb) = l8;
    };

    // ---- prologue: tile0 -> buf0, B(0) -> regs, tile1 -> slot1 ----
    LDA(0, 0);
    LDBL(0); LDBH(0);
    LDA(1, 1);
    CVTW(0, 0);                  // compiler waits only the slot-0 loads
    asm volatile("s_waitcnt lgkmcnt(0)" ::: "memory");
    __builtin_amdgcn_s_barrier();

    // ---- main loop: fully unrolled; ONE lgkm-barrier per step ----
#pragma unroll
    for (int t = 0; t < NT; ++t) {
        if (t + 2 < NT) LDA((t + 2) & 1, t + 2);   // depth-2 A prefetch (HBM)

        f16x8 ahf[4], alf[4];
#pragma unroll
        for (int m = 0; m < 4; ++m) {
            ahf[m] = *(const f16x8*)(smem + AB(t & 1) + fa + m * 1024);
            alf[m] = *(const f16x8*)(smem + AB(t & 1) + 4096 + fa + m * 1024);
        }
        if (t + 1 < NT) CVTW((t + 1) & 1, (t + 1) & 1);  // publish A(t+1) -> other buf
        asm volatile("s_waitcnt lgkmcnt(0)" ::: "memory");
        __builtin_amdgcn_s_barrier();

        // 3 passes, order identical to R2-R6 (bit-identical accumulation)
        __builtin_amdgcn_s_setprio(1);
#pragma unroll
        for (int m = 0; m < 4; ++m)
#pragma unroll
            for (int n = 0; n < 4; ++n)
                acc[m][n] = __builtin_amdgcn_mfma_f32_16x16x32_f16(ahf[m], bfh[n], acc[m][n], 0, 0, 0);
#pragma unroll
        for (int m = 0; m < 4; ++m)
#pragma unroll
            for (int n = 0; n < 4; ++n)
                acc[m][n] = __builtin_amdgcn_mfma_f32_16x16x32_f16(ahf[m], bfl[n], acc[m][n], 0, 0, 0);
        __builtin_amdgcn_s_setprio(0);
        if (t + 1 < NT) LDBL(t + 1);               // bfl dead after pass 2
        __builtin_amdgcn_s_setprio(1);
#pragma unroll
        for (int m = 0; m < 4; ++m)
#pragma unroll
            for (int n = 0; n < 4; ++n)
                acc[m][n] = __builtin_amdgcn_mfma_f32_16x16x32_f16(alf[m], bfh[n], acc[m][n], 0, 0, 0);
        __builtin_amdgcn_s_setprio(0);
        if (t + 1 < NT) LDBH(t + 1);               // bfh dead after pass 3
    }
    __syncthreads();   // full drain before overlaying smem

    // ---- epilogue (overlay scratch on smem; R5/R10-proven logic) ----
    float* rowssq = (float*)smem;                 // 256 B
    float* wvalp  = (float*)(smem + 256);         // 1 KiB
    int*   wcolp  = (int*)(smem + 1280);          // 1 KiB

    ssq += __shfl_xor(ssq, 1);
    ssq += __shfl_xor(ssq, 2);
    if (achk == 0) rowssq[arow] = ssq;

    // per-row argmax. acc[m][n][j] = S[16m + 4g + j][64wv + 16n + l15]
#pragma unroll
    for (int m = 0; m < 4; ++m) {
#pragma unroll
        for (int j = 0; j < 4; ++j) {
            float best = acc[m][0][j];
            int   bc   = 64*wv + l15;
#pragma unroll
            for (int n = 1; n < 4; ++n) {
                float v = acc[m][n][j];
                int   c = 64*wv + 16*n + l15;
                if (v > best) { best = v; bc = c; }
            }
#pragma unroll
            for (int off = 1; off < 16; off <<= 1) {
                float ov = __shfl_xor(best, off);
                int   oc = __shfl_xor(bc, off);
                if (ov > best || (ov == best && oc < bc)) { best = ov; bc = oc; }
            }
            if (l15 == 0) {
                wvalp[wv * BM + 16*m + 4*g + j] = best;
                wcolp[wv * BM + 16*m + 4*g + j] = bc;
            }
        }
    }
    __syncthreads();

    if (tid < BM) {
        int r = tid;
        float best = wvalp[r]; int bc = wcolp[r];
#pragma unroll
        for (int w = 1; w < 4; ++w) {
            float ov = wvalp[w * BM + r]; int oc = wcolp[w * BM + r];
            if (ov > best || (ov == best && oc < bc)) { best = ov; bc = oc; }
        }
        float inv = 1.f / fmaxf(sqrtf(rowssq[r]), EPS);
        int gr = row0 + r;
        out[gr]        = (float)bc;
        out[NTOT + gr] = (float)PA[bc];
        float lsum = -(best * inv) * W[gr];
#pragma unroll
        for (int off = 32; off >= 1; off >>= 1) lsum += __shfl_xor(lsum, off);
        if (tid == 0) partial[blockIdx.x] = lsum;
    }
}

// ---------------------------------------------------------------------------
// Deterministic final loss reduction: 4096 partials -> mean
// ---------------------------------------------------------------------------
__global__ void loss_reduce(const float* __restrict__ partial, float* __restrict__ out_loss) {
    __shared__ float s[256];
    float v = 0.f;
    for (int i = threadIdx.x; i < GRID_MAIN; i += 256) v += partial[i];
    s[threadIdx.x] = v;
    __syncthreads();
    for (int off = 128; off >= 1; off >>= 1) {
        if ((int)threadIdx.x < off) s[threadIdx.x] += s[threadIdx.x + off];
        __syncthreads();
    }
    if (threadIdx.x == 0) out_loss[0] = s[0] * (1.0f / (float)NTOT);
}

extern "C" void kernel_launch(void* const* d_in, const int* in_sizes, int n_in,
                              void* d_out, int out_size, void* d_ws, size_t ws_size,
                              hipStream_t stream) {
    const float* features = (const float*)d_in[0];
    const float* weight   = (const float*)d_in[1];
    const float* cc       = (const float*)d_in[2];
    const int*   pa       = (const int*)d_in[3];
    float* out = (float*)d_out;

    _Float16* bh   = (_Float16*)d_ws;              // 192 KiB fragment-order hi
    _Float16* bl   = bh + KCL * DIM;               // 192 KiB fragment-order lo
    float* partial = (float*)(bl + KCL * DIM);     // 16 KiB

    hipLaunchKernelGGL(prep_clusters, dim3(KCL), dim3(64), 0, stream, cc, bh, bl);
    hipLaunchKernelGGL(kmeans_main, dim3(GRID_MAIN), dim3(TBS), 0, stream,
                       features, weight, bh, bl, pa, out, partial);
    hipLaunchKernelGGL(loss_reduce, dim3(1), dim3(256), 0, stream, partial, out + 2 * NTOT);
}